// Round 8
// baseline (339.806 us; speedup 1.0000x reference)
//
#include <hip/hip_runtime.h>
#include <stdint.h>

// VQ argmin, bit-replicating numpy fp32 reference (see R2).
// R14: scalar-pipe codebook. R6-R13 all orbit ~200-250us: the LDS-staging
// structure pays ~123us LDS-pipe + ~143us VALU with imperfect overlap, and
// occupancy reads ~19% regardless of knobs. Structural fix: the codebook is
// WAVE-UNIFORM data -> belongs in SGPRs, not LDS. Re-map lane=pixel (64/blk),
// wave=64-code chunk: c[d][j] via s_load (K$/lgkm pipe; v_fmac reads the
// SGPR directly), z[d][pix] via 1 coalesced global_load_dword/dim (VMEM).
// Main loop uses ZERO LDS, zero barriers, zero staging VALU -> VALU is the
// only loaded pipe (floor ~109us). acc[64] scalar ascending-d fmaf chains
// -> BIT-EXACT (absmax must stay 1.907349e-06). 512-thr blocks (8 waves),
// SPLIT=4 -> grid 1024; workspace layout unchanged. readfirstlane forces
// the c-pointer uniform so the compiler scalarizes the loads.
// B=16 D=256 H=W=32 -> n=16384 pixels; K=2048 codes.

#define D_    256
#define K_    2048
#define HW_   1024
#define MT    64      // pixels per block
#define SPLIT 4
#define KS    (K_ / SPLIT)   // 512 codes per block (8 waves x 64)
#define NPIX  16384

// numpy pairwise combine of 8 accumulators
__device__ __forceinline__ float pw8(const float r[8]) {
    float t01 = __fadd_rn(r[0], r[1]);
    float t23 = __fadd_rn(r[2], r[3]);
    float L   = __fadd_rn(t01, t23);
    float t45 = __fadd_rn(r[4], r[5]);
    float t67 = __fadd_rn(r[6], r[7]);
    float R   = __fadd_rn(t45, t67);
    return __fadd_rn(L, R);
}

// prep: blocks [0,128) transpose cb->ct; [128,136) Bn; [136,200) An
__global__ __launch_bounds__(256) void prep_k(const float* __restrict__ z,
                                              const float* __restrict__ cb,
                                              float* __restrict__ ct,
                                              float* __restrict__ An,
                                              float* __restrict__ Bn) {
    __shared__ float t[64][65];
    int tid = threadIdx.x;
    int bx  = blockIdx.x;
    if (bx < 128) {
        int k0 = (bx & 31) << 6;
        int d0 = (bx >> 5) << 6;
        #pragma unroll
        for (int it = 0; it < 4; ++it) {
            int u  = (it << 8) + tid;
            int kk = u >> 4;
            int dd = (u & 15) << 2;
            float4 v = *reinterpret_cast<const float4*>(
                cb + (size_t)(k0 + kk) * D_ + d0 + dd);
            t[kk][dd + 0] = v.x; t[kk][dd + 1] = v.y;
            t[kk][dd + 2] = v.z; t[kk][dd + 3] = v.w;
        }
        __syncthreads();
        #pragma unroll
        for (int it = 0; it < 4; ++it) {
            int u  = (it << 8) + tid;
            int dd = u >> 4;
            int kk = (u & 15) << 2;
            float4 o;
            o.x = t[kk + 0][dd]; o.y = t[kk + 1][dd];
            o.z = t[kk + 2][dd]; o.w = t[kk + 3][dd];
            *reinterpret_cast<float4*>(ct + (size_t)(d0 + dd) * K_ + k0 + kk) = o;
        }
    } else if (bx < 136) {
        int row = (bx - 128) * 256 + tid;
        const float4* p = reinterpret_cast<const float4*>(cb + (size_t)row * D_);
        float rA[8], rB[8];
        #pragma unroll
        for (int j = 0; j < 8; ++j) { rA[j] = 0.f; rB[j] = 0.f; }
        #pragma unroll
        for (int q = 0; q < 64; ++q) {
            float4 v = p[q];
            float pv[4] = {__fmul_rn(v.x, v.x), __fmul_rn(v.y, v.y),
                           __fmul_rn(v.z, v.z), __fmul_rn(v.w, v.w)};
            if (q < 32) {
                #pragma unroll
                for (int l = 0; l < 4; ++l)
                    rA[(4 * q + l) & 7] = __fadd_rn(rA[(4 * q + l) & 7], pv[l]);
            } else {
                #pragma unroll
                for (int l = 0; l < 4; ++l)
                    rB[(4 * q + l) & 7] = __fadd_rn(rB[(4 * q + l) & 7], pv[l]);
            }
        }
        Bn[row] = __fadd_rn(pw8(rA), pw8(rB));
    } else {
        int blk = bx - 136;                  // [0,64): 256 pixels each
        int b   = blk >> 2;
        int hw0 = (blk & 3) << 8;
        const float* zb = z + (size_t)b * (D_ * HW_) + hw0 + tid;
        float rA[8], rB[8];
        #pragma unroll
        for (int j = 0; j < 8; ++j) { rA[j] = 0.f; rB[j] = 0.f; }
        #pragma unroll 8
        for (int d = 0; d < 128; ++d) {      // coalesced: consecutive threads
            float v = zb[(size_t)d * HW_];
            rA[d & 7] = __fadd_rn(rA[d & 7], __fmul_rn(v, v));
        }
        #pragma unroll 8
        for (int d = 128; d < 256; ++d) {
            float v = zb[(size_t)d * HW_];
            rB[d & 7] = __fadd_rn(rB[d & 7], __fmul_rn(v, v));
        }
        An[(size_t)b * HW_ + hw0 + tid] = __fadd_rn(pw8(rA), pw8(rB));
    }
}

// main GEMM+argmin: lane=pixel, wave=64 codes; c via scalar loads, z via VMEM
__global__ __launch_bounds__(512, 2) void vq_k(const float* __restrict__ z,
                                               const float* __restrict__ ct,
                                               const float* __restrict__ An,
                                               const float* __restrict__ Bn,
                                               float* __restrict__ pscore,
                                               int* __restrict__ pidx) {
    __shared__ float rs[512];
    __shared__ int   ri[512];

    const int tid  = threadIdx.x;
    const int lane = tid & 63;                    // pixel within block
    const int wu   = __builtin_amdgcn_readfirstlane(tid >> 6);  // wave [0,8)
    const int blk  = blockIdx.x;
    const int p    = blk / SPLIT;                 // pixel-block [0,256)
    const int s    = blk % SPLIT;                 // K-split slice
    const int b      = p >> 4;
    const int hwbase = (p & 15) << 6;

    const int code0 = s * KS + (wu << 6);         // this wave's 64 codes
    const float* zp = z + (size_t)b * (D_ * HW_) + hwbase + lane;
    const float* cp = ct + code0;                 // row d at cp + d*K_

    float acc[64];
    #pragma unroll
    for (int j = 0; j < 64; ++j) acc[j] = 0.f;

    // ascending-d fmaf chain per code — bit-matches sgemm
    for (int d = 0; d < D_; ++d) {
        float zv = zp[(size_t)d * HW_];           // coalesced VMEM (256B/wave)
        const float* cr = cp + (size_t)d * K_;    // uniform -> s_load
        #pragma unroll
        for (int j = 0; j < 64; ++j)
            acc[j] = fmaf(zv, cr[j], acc[j]);
    }

    // per-lane argmin over this wave's 64 codes (ascending -> first-min)
    float an = An[(size_t)b * HW_ + hwbase + lane];
    const float* bp = Bn + code0;                 // uniform -> s_load
    float best = 1e30f; int bidx = 0;
    #pragma unroll
    for (int j = 0; j < 64; ++j) {
        float sc = __fsub_rn(__fadd_rn(an, bp[j]),
                             __fmul_rn(2.0f, acc[j]));
        if (sc < best) { best = sc; bidx = code0 + j; }
    }

    // cross-wave merge (ascending wave order keeps lowest-index tiebreak)
    rs[(wu << 6) + lane] = best;
    ri[(wu << 6) + lane] = bidx;
    __syncthreads();
    if (tid < MT) {
        float bb = rs[tid]; int bx = ri[tid];
        #pragma unroll
        for (int t = 1; t < 8; ++t) {
            float sv = rs[(t << 6) + tid];
            int   ix = ri[(t << 6) + tid];
            if (sv < bb || (sv == bb && ix < bx)) { bb = sv; bx = ix; }
        }
        int g = b * HW_ + hwbase + tid;
        pscore[s * NPIX + g] = bb;
        pidx[s * NPIX + g]   = bx;
    }
}

// merge SPLIT partials (first-min tiebreak) + gather output
__global__ __launch_bounds__(256) void fin_k(const float* __restrict__ cb,
                                             const float* __restrict__ pscore,
                                             const int* __restrict__ pidx,
                                             float* __restrict__ out) {
    __shared__ int idxs[MT];
    int tid = threadIdx.x;
    int p   = blockIdx.x;               // [0,256)
    int b      = p >> 4;
    int hwbase = (p & 15) << 6;
    if (tid < MT) {
        int g = b * HW_ + hwbase + tid;
        float best = pscore[g];
        int   bidx = pidx[g];
        #pragma unroll
        for (int s = 1; s < SPLIT; ++s) {
            float sv = pscore[s * NPIX + g];
            int   ix = pidx[s * NPIX + g];
            if (sv < best || (sv == best && ix < bidx)) { best = sv; bidx = ix; }
        }
        idxs[tid] = bidx;
    }
    __syncthreads();
    float* obase = out + (size_t)b * (D_ * HW_) + hwbase;
    #pragma unroll
    for (int it = 0; it < 16; ++it) {
        int u  = (it << 8) + tid;
        int dd = u >> 4;                // [0,256)
        int m4 = u & 15;
        int i0 = idxs[(m4 << 2) + 0];
        int i1 = idxs[(m4 << 2) + 1];
        int i2 = idxs[(m4 << 2) + 2];
        int i3 = idxs[(m4 << 2) + 3];
        float4 o;
        o.x = cb[(size_t)i0 * D_ + dd];
        o.y = cb[(size_t)i1 * D_ + dd];
        o.z = cb[(size_t)i2 * D_ + dd];
        o.w = cb[(size_t)i3 * D_ + dd];
        *reinterpret_cast<float4*>(obase + (size_t)dd * HW_ + (m4 << 2)) = o;
    }
}

extern "C" void kernel_launch(void* const* d_in, const int* in_sizes, int n_in,
                              void* d_out, int out_size, void* d_ws, size_t ws_size,
                              hipStream_t stream) {
    const float* z  = (const float*)d_in[0];   // 16*256*32*32
    const float* cb = (const float*)d_in[1];   // 2048*256
    float* pscore = (float*)d_ws;                       // 4*16384
    int*   pidx   = (int*)(pscore + SPLIT * NPIX);      // 4*16384
    float* An     = (float*)(pidx + SPLIT * NPIX);      // 16384
    float* Bn     = An + NPIX;                          // 2048
    float* ct     = Bn + K_;                            // 256*2048 (2 MB)
    float* out    = (float*)d_out;

    prep_k<<<dim3(200), dim3(256), 0, stream>>>(z, cb, ct, An, Bn);
    vq_k<<<dim3(256 * SPLIT), dim3(512), 0, stream>>>(z, ct, An, Bn, pscore, pidx);
    fin_k<<<dim3(256), dim3(256), 0, stream>>>(cb, pscore, pidx, out);
}

// Round 9
// 298.241 us; speedup vs baseline: 1.1394x; 1.1394x over previous
//
#include <hip/hip_runtime.h>
#include <stdint.h>

// VQ argmin, bit-replicating numpy fp32 reference (see R2).
// R15: scalar-pipe codebook, coverage fix. R14 proved the structure: VALU
// busy time 123us ~= the 109us FMA floor (VGPR 40, zero LDS/barriers in
// loop), but 512-thr blocks left only ~1.75 blocks/CU resident -> 155us of
// uncovered s_load latency (16 s_loads ~250-300cyc vs 128cyc FMA burst =
// 33% duty x 3.5 waves = the measured 44% VALUBusy). Fix: 256-thr blocks
// (4 waves, 1 wave/SIMD granularity; the shape that co-resides 4+/CU in
// R6/R8/R13) at grid 1024 = 4 blocks/CU -> 4 waves/SIMD x 33% duty = 136%
// demand -> VALU saturates. Block covers its 512 codes in two sequential
// 256-code halves (4 waves x 64/half), best/bidx carried across halves
// (indices ascend; strict < keeps first-min). z re-read per half (VMEM,
// L3-resident). Ascending-d fmaf chains -> BIT-EXACT (absmax 1.907349e-06).
// B=16 D=256 H=W=32 -> n=16384 pixels; K=2048 codes.

#define D_    256
#define K_    2048
#define HW_   1024
#define MT    64      // pixels per block
#define SPLIT 4
#define KS    (K_ / SPLIT)   // 512 codes per block (2 halves x 4 waves x 64)
#define NPIX  16384

// numpy pairwise combine of 8 accumulators
__device__ __forceinline__ float pw8(const float r[8]) {
    float t01 = __fadd_rn(r[0], r[1]);
    float t23 = __fadd_rn(r[2], r[3]);
    float L   = __fadd_rn(t01, t23);
    float t45 = __fadd_rn(r[4], r[5]);
    float t67 = __fadd_rn(r[6], r[7]);
    float R   = __fadd_rn(t45, t67);
    return __fadd_rn(L, R);
}

// prep: blocks [0,128) transpose cb->ct; [128,136) Bn; [136,200) An
__global__ __launch_bounds__(256) void prep_k(const float* __restrict__ z,
                                              const float* __restrict__ cb,
                                              float* __restrict__ ct,
                                              float* __restrict__ An,
                                              float* __restrict__ Bn) {
    __shared__ float t[64][65];
    int tid = threadIdx.x;
    int bx  = blockIdx.x;
    if (bx < 128) {
        int k0 = (bx & 31) << 6;
        int d0 = (bx >> 5) << 6;
        #pragma unroll
        for (int it = 0; it < 4; ++it) {
            int u  = (it << 8) + tid;
            int kk = u >> 4;
            int dd = (u & 15) << 2;
            float4 v = *reinterpret_cast<const float4*>(
                cb + (size_t)(k0 + kk) * D_ + d0 + dd);
            t[kk][dd + 0] = v.x; t[kk][dd + 1] = v.y;
            t[kk][dd + 2] = v.z; t[kk][dd + 3] = v.w;
        }
        __syncthreads();
        #pragma unroll
        for (int it = 0; it < 4; ++it) {
            int u  = (it << 8) + tid;
            int dd = u >> 4;
            int kk = (u & 15) << 2;
            float4 o;
            o.x = t[kk + 0][dd]; o.y = t[kk + 1][dd];
            o.z = t[kk + 2][dd]; o.w = t[kk + 3][dd];
            *reinterpret_cast<float4*>(ct + (size_t)(d0 + dd) * K_ + k0 + kk) = o;
        }
    } else if (bx < 136) {
        int row = (bx - 128) * 256 + tid;
        const float4* p = reinterpret_cast<const float4*>(cb + (size_t)row * D_);
        float rA[8], rB[8];
        #pragma unroll
        for (int j = 0; j < 8; ++j) { rA[j] = 0.f; rB[j] = 0.f; }
        #pragma unroll
        for (int q = 0; q < 64; ++q) {
            float4 v = p[q];
            float pv[4] = {__fmul_rn(v.x, v.x), __fmul_rn(v.y, v.y),
                           __fmul_rn(v.z, v.z), __fmul_rn(v.w, v.w)};
            if (q < 32) {
                #pragma unroll
                for (int l = 0; l < 4; ++l)
                    rA[(4 * q + l) & 7] = __fadd_rn(rA[(4 * q + l) & 7], pv[l]);
            } else {
                #pragma unroll
                for (int l = 0; l < 4; ++l)
                    rB[(4 * q + l) & 7] = __fadd_rn(rB[(4 * q + l) & 7], pv[l]);
            }
        }
        Bn[row] = __fadd_rn(pw8(rA), pw8(rB));
    } else {
        int blk = bx - 136;                  // [0,64): 256 pixels each
        int b   = blk >> 2;
        int hw0 = (blk & 3) << 8;
        const float* zb = z + (size_t)b * (D_ * HW_) + hw0 + tid;
        float rA[8], rB[8];
        #pragma unroll
        for (int j = 0; j < 8; ++j) { rA[j] = 0.f; rB[j] = 0.f; }
        #pragma unroll 8
        for (int d = 0; d < 128; ++d) {      // coalesced: consecutive threads
            float v = zb[(size_t)d * HW_];
            rA[d & 7] = __fadd_rn(rA[d & 7], __fmul_rn(v, v));
        }
        #pragma unroll 8
        for (int d = 128; d < 256; ++d) {
            float v = zb[(size_t)d * HW_];
            rB[d & 7] = __fadd_rn(rB[d & 7], __fmul_rn(v, v));
        }
        An[(size_t)b * HW_ + hw0 + tid] = __fadd_rn(pw8(rA), pw8(rB));
    }
}

// main GEMM+argmin: lane=pixel, wave=64 codes x 2 halves; c scalar, z VMEM
__global__ __launch_bounds__(256, 2) void vq_k(const float* __restrict__ z,
                                               const float* __restrict__ ct,
                                               const float* __restrict__ An,
                                               const float* __restrict__ Bn,
                                               float* __restrict__ pscore,
                                               int* __restrict__ pidx) {
    __shared__ float rs[256];
    __shared__ int   ri[256];

    const int tid  = threadIdx.x;
    const int lane = tid & 63;                    // pixel within block
    const int wu   = __builtin_amdgcn_readfirstlane(tid >> 6);  // wave [0,4)
    const int blk  = blockIdx.x;
    const int p    = blk / SPLIT;                 // pixel-block [0,256)
    const int s    = blk % SPLIT;                 // K-split slice
    const int b      = p >> 4;
    const int hwbase = (p & 15) << 6;

    const float* zp = z + (size_t)b * (D_ * HW_) + hwbase + lane;
    const float an  = An[(size_t)b * HW_ + hwbase + lane];

    float best = 1e30f; int bidx = 0;

    #pragma unroll 1
    for (int h = 0; h < 2; ++h) {
        const int code0 = s * KS + (h << 8) + (wu << 6);  // this wave's 64 codes
        const float* cp = ct + code0;             // row d at cp + d*K_ (uniform)

        float acc[64];
        #pragma unroll
        for (int j = 0; j < 64; ++j) acc[j] = 0.f;

        // ascending-d fmaf chain per code — bit-matches sgemm
        for (int d = 0; d < D_; ++d) {
            float zv = zp[(size_t)d * HW_];       // coalesced VMEM (256B/wave)
            const float* cr = cp + (size_t)d * K_;  // uniform -> s_load
            #pragma unroll
            for (int j = 0; j < 64; ++j)
                acc[j] = fmaf(zv, cr[j], acc[j]);
        }

        // per-lane argmin (ascending j, strict < -> first-min; halves ascend)
        const float* bp = Bn + code0;             // uniform -> s_load
        #pragma unroll
        for (int j = 0; j < 64; ++j) {
            float sc = __fsub_rn(__fadd_rn(an, bp[j]),
                                 __fmul_rn(2.0f, acc[j]));
            if (sc < best) { best = sc; bidx = code0 + j; }
        }
    }

    // cross-wave merge (index tiebreak handles interleaved half/wave order)
    rs[(wu << 6) + lane] = best;
    ri[(wu << 6) + lane] = bidx;
    __syncthreads();
    if (tid < MT) {
        float bb = rs[tid]; int bx = ri[tid];
        #pragma unroll
        for (int t = 1; t < 4; ++t) {
            float sv = rs[(t << 6) + tid];
            int   ix = ri[(t << 6) + tid];
            if (sv < bb || (sv == bb && ix < bx)) { bb = sv; bx = ix; }
        }
        int g = b * HW_ + hwbase + tid;
        pscore[s * NPIX + g] = bb;
        pidx[s * NPIX + g]   = bx;
    }
}

// merge SPLIT partials (first-min tiebreak) + gather output
__global__ __launch_bounds__(256) void fin_k(const float* __restrict__ cb,
                                             const float* __restrict__ pscore,
                                             const int* __restrict__ pidx,
                                             float* __restrict__ out) {
    __shared__ int idxs[MT];
    int tid = threadIdx.x;
    int p   = blockIdx.x;               // [0,256)
    int b      = p >> 4;
    int hwbase = (p & 15) << 6;
    if (tid < MT) {
        int g = b * HW_ + hwbase + tid;
        float best = pscore[g];
        int   bidx = pidx[g];
        #pragma unroll
        for (int s = 1; s < SPLIT; ++s) {
            float sv = pscore[s * NPIX + g];
            int   ix = pidx[s * NPIX + g];
            if (sv < best || (sv == best && ix < bidx)) { best = sv; bidx = ix; }
        }
        idxs[tid] = bidx;
    }
    __syncthreads();
    float* obase = out + (size_t)b * (D_ * HW_) + hwbase;
    #pragma unroll
    for (int it = 0; it < 16; ++it) {
        int u  = (it << 8) + tid;
        int dd = u >> 4;                // [0,256)
        int m4 = u & 15;
        int i0 = idxs[(m4 << 2) + 0];
        int i1 = idxs[(m4 << 2) + 1];
        int i2 = idxs[(m4 << 2) + 2];
        int i3 = idxs[(m4 << 2) + 3];
        float4 o;
        o.x = cb[(size_t)i0 * D_ + dd];
        o.y = cb[(size_t)i1 * D_ + dd];
        o.z = cb[(size_t)i2 * D_ + dd];
        o.w = cb[(size_t)i3 * D_ + dd];
        *reinterpret_cast<float4*>(obase + (size_t)dd * HW_ + (m4 << 2)) = o;
    }
}

extern "C" void kernel_launch(void* const* d_in, const int* in_sizes, int n_in,
                              void* d_out, int out_size, void* d_ws, size_t ws_size,
                              hipStream_t stream) {
    const float* z  = (const float*)d_in[0];   // 16*256*32*32
    const float* cb = (const float*)d_in[1];   // 2048*256
    float* pscore = (float*)d_ws;                       // 4*16384
    int*   pidx   = (int*)(pscore + SPLIT * NPIX);      // 4*16384
    float* An     = (float*)(pidx + SPLIT * NPIX);      // 16384
    float* Bn     = An + NPIX;                          // 2048
    float* ct     = Bn + K_;                            // 256*2048 (2 MB)
    float* out    = (float*)d_out;

    prep_k<<<dim3(200), dim3(256), 0, stream>>>(z, cb, ct, An, Bn);
    vq_k<<<dim3(256 * SPLIT), dim3(256), 0, stream>>>(z, ct, An, Bn, pscore, pidx);
    fin_k<<<dim3(256), dim3(256), 0, stream>>>(cb, pscore, pidx, out);
}